// Round 1
// baseline (325.672 us; speedup 1.0000x reference)
//
#include <hip/hip_runtime.h>

// ProbabilityMatrix: 4x row-histogram of per-patch popcounts, normalized.
// ws layout (ints) == out layout (floats), flat concat:
//   box0 [16][16] @ 0, box1 [16][64] @ 256, box2 [16][16] @ 1280, box3 [16][64] @ 1536
// total 2560.

#define P_PATCH 32768
#define B_ROWS  16
#define NPATCH  (B_ROWS * P_PATCH)   // 524288 patches per box

template <int S2, int VEC>  // VEC = S2/4 float4 per patch
__device__ __forceinline__ void hist_box(const float4* __restrict__ in,
                                         int* __restrict__ gcounts,
                                         int block_rank, int num_blocks,
                                         int* lds) {
    // zero the per-block histogram [16][S2]
    for (int i = threadIdx.x; i < B_ROWS * S2; i += 256) lds[i] = 0;
    __syncthreads();

    const int nthreads = num_blocks * 256;
    for (int g = block_rank * 256 + (int)threadIdx.x; g < NPATCH; g += nthreads) {
        const float4* p = in + (size_t)g * VEC;
        float s = 0.f;
#pragma unroll
        for (int j = 0; j < VEC; ++j) {
            float4 v = p[j];
            s += (v.x + v.y) + (v.z + v.w);
        }
        int bin = (int)(s + 0.5f);   // exact: sums of 0.0/1.0
        int b = g >> 15;             // g / P_PATCH
        if (bin < S2)                // drop popcount == S2 (TF bincount maxlength semantics)
            atomicAdd(&lds[b * S2 + bin], 1);
    }
    __syncthreads();

    for (int i = threadIdx.x; i < B_ROWS * S2; i += 256) {
        int c = lds[i];
        if (c) atomicAdd(&gcounts[i], c);
    }
}

__global__ __launch_bounds__(256) void hist_kernel(const float4* __restrict__ in0,
                                                   const float4* __restrict__ in1,
                                                   const float4* __restrict__ in2,
                                                   const float4* __restrict__ in3,
                                                   int* __restrict__ ws) {
    __shared__ int lds[B_ROWS * 64];  // 4 KiB, max of both box shapes
    const int bid = blockIdx.x;
    if (bid < 128)      hist_box<16, 4 >(in0, ws + 0,    bid,       128, lds);
    else if (bid < 640) hist_box<64, 16>(in1, ws + 256,  bid - 128, 512, lds);
    else if (bid < 768) hist_box<16, 4 >(in2, ws + 1280, bid - 640, 128, lds);
    else                hist_box<64, 16>(in3, ws + 1536, bid - 768, 512, lds);
}

// one 64-lane wave per (box,row): out[v] = counts[v] / rowsum
__global__ __launch_bounds__(64) void norm_kernel(const int* __restrict__ ws,
                                                  float* __restrict__ out) {
    const int row  = blockIdx.x;      // 0..63
    const int lane = threadIdx.x;     // 0..63
    const int box  = row >> 4;
    const int r    = row & 15;
    const int bins = (box & 1) ? 64 : 16;
    int off = (box == 0) ? 0 : (box == 1) ? 256 : (box == 2) ? 1280 : 1536;
    off += r * bins;

    int c = (lane < bins) ? ws[off + lane] : 0;
    int total = c;
#pragma unroll
    for (int d = 32; d > 0; d >>= 1) total += __shfl_down(total, d);
    total = __shfl(total, 0);

    if (lane < bins) out[off + lane] = (float)c / (float)total;
}

extern "C" void kernel_launch(void* const* d_in, const int* in_sizes, int n_in,
                              void* d_out, int out_size, void* d_ws, size_t ws_size,
                              hipStream_t stream) {
    const float4* in0 = (const float4*)d_in[0];  // cd0_box0 [16,32768,4,4]
    const float4* in1 = (const float4*)d_in[1];  // cd0_box1 [16,32768,8,8]
    const float4* in2 = (const float4*)d_in[2];  // cd1_box0 [16,32768,4,4]
    const float4* in3 = (const float4*)d_in[3];  // cd1_box1 [16,32768,8,8]
    int* ws = (int*)d_ws;

    hipMemsetAsync(ws, 0, 2560 * sizeof(int), stream);
    hist_kernel<<<1280, 256, 0, stream>>>(in0, in1, in2, in3, ws);
    norm_kernel<<<64, 64, 0, stream>>>(ws, (float*)d_out);
}

// Round 2
// 319.770 us; speedup vs baseline: 1.0185x; 1.0185x over previous
//
#include <hip/hip_runtime.h>

// ProbabilityMatrix: 4x row-histogram of per-patch popcounts, normalized.
// ws layout (ints) == out layout (floats), flat concat:
//   box0 [16][16] @ 0, box1 [16][64] @ 256, box2 [16][16] @ 1280, box3 [16][64] @ 1536

#define P_PATCH 32768
#define B_ROWS  16
#define NPATCH  (B_ROWS * P_PATCH)   // 524288 patches per box

// Coalesced scheme: lane i loads float4 at (tile_base + k*256 + tid).
// FV consecutive lanes own one patch (FV*16B = patch bytes). Patch popcount
// via log2(FV) shfl_xor steps; group leader does one LDS atomic per patch.
template <int FV, int LOG2FV>  // FV = float4 per patch (4 or 16)
__device__ __forceinline__ void hist_box(const float4* __restrict__ in,
                                         int* __restrict__ gcounts,
                                         int block_rank, int num_blocks,
                                         int* lds) {
    constexpr int S2 = FV * 4;
    constexpr int U  = 4;                      // float4 per thread per tile
    const int N4     = NPATCH * FV;            // total float4 in box
    const int ntiles = N4 / (256 * U);         // exact: N4 is 2^21 or 2^23

    for (int i = threadIdx.x; i < B_ROWS * S2; i += 256) lds[i] = 0;
    __syncthreads();

    const int lane_grp = threadIdx.x & (FV - 1);

    for (int t = block_rank; t < ntiles; t += num_blocks) {
        const int base = t * (256 * U) + (int)threadIdx.x;
        float4 v[U];
#pragma unroll
        for (int k = 0; k < U; ++k) v[k] = in[base + k * 256];  // coalesced, 4 in flight
#pragma unroll
        for (int k = 0; k < U; ++k) {
            float s = (v[k].x + v[k].y) + (v[k].z + v[k].w);
#pragma unroll
            for (int off = 1; off < FV; off <<= 1) s += __shfl_xor(s, off);
            if (lane_grp == 0) {
                const int q     = base + k * 256;
                const int patch = q >> LOG2FV;
                const int row   = patch >> 15;        // patch / P_PATCH
                const int bin   = (int)(s + 0.5f);    // exact: sum of 0/1 floats
                if (bin < S2)                          // drop popcount == S2 (TF semantics)
                    atomicAdd(&lds[row * S2 + bin], 1);
            }
        }
    }
    __syncthreads();

    for (int i = threadIdx.x; i < B_ROWS * S2; i += 256) {
        int c = lds[i];
        if (c) atomicAdd(&gcounts[i], c);
    }
}

#define NB0 384
#define NB1 1536

__global__ __launch_bounds__(256) void hist_kernel(const float4* __restrict__ in0,
                                                   const float4* __restrict__ in1,
                                                   const float4* __restrict__ in2,
                                                   const float4* __restrict__ in3,
                                                   int* __restrict__ ws) {
    __shared__ int lds[B_ROWS * 64];  // 4 KiB, max of both box shapes
    const int bid = blockIdx.x;
    if (bid < NB0)                  hist_box<4, 2>(in0, ws + 0,    bid,                 NB0, lds);
    else if (bid < NB0 + NB1)       hist_box<16,4>(in1, ws + 256,  bid - NB0,           NB1, lds);
    else if (bid < 2*NB0 + NB1)     hist_box<4, 2>(in2, ws + 1280, bid - NB0 - NB1,     NB0, lds);
    else                            hist_box<16,4>(in3, ws + 1536, bid - 2*NB0 - NB1,   NB1, lds);
}

// one 64-lane wave per (box,row): out[v] = counts[v] / rowsum
__global__ __launch_bounds__(64) void norm_kernel(const int* __restrict__ ws,
                                                  float* __restrict__ out) {
    const int row  = blockIdx.x;      // 0..63
    const int lane = threadIdx.x;     // 0..63
    const int box  = row >> 4;
    const int r    = row & 15;
    const int bins = (box & 1) ? 64 : 16;
    int off = (box == 0) ? 0 : (box == 1) ? 256 : (box == 2) ? 1280 : 1536;
    off += r * bins;

    int c = (lane < bins) ? ws[off + lane] : 0;
    int total = c;
#pragma unroll
    for (int d = 32; d > 0; d >>= 1) total += __shfl_down(total, d);
    total = __shfl(total, 0);

    if (lane < bins) out[off + lane] = (float)c / (float)total;
}

extern "C" void kernel_launch(void* const* d_in, const int* in_sizes, int n_in,
                              void* d_out, int out_size, void* d_ws, size_t ws_size,
                              hipStream_t stream) {
    const float4* in0 = (const float4*)d_in[0];  // cd0_box0 [16,32768,4,4]
    const float4* in1 = (const float4*)d_in[1];  // cd0_box1 [16,32768,8,8]
    const float4* in2 = (const float4*)d_in[2];  // cd1_box0 [16,32768,4,4]
    const float4* in3 = (const float4*)d_in[3];  // cd1_box1 [16,32768,8,8]
    int* ws = (int*)d_ws;

    hipMemsetAsync(ws, 0, 2560 * sizeof(int), stream);
    hist_kernel<<<2 * (NB0 + NB1), 256, 0, stream>>>(in0, in1, in2, in3, ws);
    norm_kernel<<<64, 64, 0, stream>>>(ws, (float*)d_out);
}

// Round 3
// 317.342 us; speedup vs baseline: 1.0263x; 1.0077x over previous
//
#include <hip/hip_runtime.h>

// ProbabilityMatrix: 4x row-histogram of per-patch popcounts, normalized.
// ws layout (ints) == out layout (floats), flat concat:
//   box0 [16][16] @ 0, box1 [16][64] @ 256, box2 [16][16] @ 1280, box3 [16][64] @ 1536

#define P_PATCH 32768
#define B_ROWS  16
#define NPATCH  (B_ROWS * P_PATCH)   // 524288 patches per box

// DPP-based partial add: s += dpp_perm(s). Pure VALU — no LDS, no ds_swizzle.
template <int CTRL>
__device__ __forceinline__ float dpp_add(float s) {
    int t = __builtin_amdgcn_update_dpp(0, __float_as_int(s), CTRL, 0xF, 0xF, true);
    return s + __int_as_float(t);
}
// ctrl encodings: quad_perm[1,0,3,2]=0xB1 (xor1), quad_perm[2,3,0,1]=0x4E (xor2),
// row_ror:4=0x124, row_ror:8=0x128 (16-lane-row rotate; rotate-allreduce).

template <int FV, int LOG2FV>  // FV = float4 per patch (4 or 16)
__device__ __forceinline__ void hist_box(const float4* __restrict__ in,
                                         int* __restrict__ gcounts,
                                         int block_rank, int num_blocks,
                                         int* lds) {
    constexpr int S2 = FV * 4;
    constexpr int U  = 8;                      // float4 per thread per tile
    const int N4     = NPATCH * FV;            // total float4 in box (2^21 or 2^23)
    const int ntiles = N4 / (256 * U);         // exact

    for (int i = threadIdx.x; i < B_ROWS * S2; i += 256) lds[i] = 0;
    __syncthreads();

    const int  tid    = (int)threadIdx.x;
    const bool leader = (tid & (FV - 1)) == 0;

    for (int t = block_rank; t < ntiles; t += num_blocks) {
        const int base = t * (256 * U) + tid;
        float4 v[U];
#pragma unroll
        for (int k = 0; k < U; ++k) v[k] = in[base + k * 256];  // coalesced, independent
#pragma unroll
        for (int k = 0; k < U; ++k) {
            float s = (v[k].x + v[k].y) + (v[k].z + v[k].w);
            s = dpp_add<0xB1>(s);              // + xor1  (quad)
            s = dpp_add<0x4E>(s);              // + xor2  (quad) -> quad sums
            if (FV == 16) {
                s = dpp_add<0x124>(s);         // + row_ror:4
                s = dpp_add<0x128>(s);         // + row_ror:8 -> 16-lane sum in all lanes
            }
            if (leader) {
                const int q     = base + k * 256;
                const int patch = q >> LOG2FV;
                const int row   = patch >> 15;       // / P_PATCH
                const int bin   = (int)(s + 0.5f);   // exact: sum of 0/1 floats
                if (bin < S2)                        // drop popcount == S2 (TF semantics)
                    atomicAdd(&lds[row * S2 + bin], 1);
            }
        }
    }
    __syncthreads();

    for (int i = threadIdx.x; i < B_ROWS * S2; i += 256) {
        int c = lds[i];
        if (c) atomicAdd(&gcounts[i], c);
    }
}

#define NB0 384
#define NB1 1536

__global__ __launch_bounds__(256) void hist_kernel(const float4* __restrict__ in0,
                                                   const float4* __restrict__ in1,
                                                   const float4* __restrict__ in2,
                                                   const float4* __restrict__ in3,
                                                   int* __restrict__ ws) {
    __shared__ int lds[B_ROWS * 64];  // 4 KiB, max of both box shapes
    const int bid = blockIdx.x;
    if (bid < NB0)              hist_box<4, 2>(in0, ws + 0,    bid,               NB0, lds);
    else if (bid < NB0 + NB1)   hist_box<16,4>(in1, ws + 256,  bid - NB0,         NB1, lds);
    else if (bid < 2*NB0 + NB1) hist_box<4, 2>(in2, ws + 1280, bid - NB0 - NB1,   NB0, lds);
    else                        hist_box<16,4>(in3, ws + 1536, bid - 2*NB0 - NB1, NB1, lds);
}

// one 64-lane wave per (box,row): out[v] = counts[v] / rowsum
__global__ __launch_bounds__(64) void norm_kernel(const int* __restrict__ ws,
                                                  float* __restrict__ out) {
    const int row  = blockIdx.x;      // 0..63
    const int lane = threadIdx.x;     // 0..63
    const int box  = row >> 4;
    const int r    = row & 15;
    const int bins = (box & 1) ? 64 : 16;
    int off = (box == 0) ? 0 : (box == 1) ? 256 : (box == 2) ? 1280 : 1536;
    off += r * bins;

    int c = (lane < bins) ? ws[off + lane] : 0;
    int total = c;
#pragma unroll
    for (int d = 32; d > 0; d >>= 1) total += __shfl_down(total, d);
    total = __shfl(total, 0);

    if (lane < bins) out[off + lane] = (float)c / (float)total;
}

extern "C" void kernel_launch(void* const* d_in, const int* in_sizes, int n_in,
                              void* d_out, int out_size, void* d_ws, size_t ws_size,
                              hipStream_t stream) {
    const float4* in0 = (const float4*)d_in[0];  // cd0_box0 [16,32768,4,4]
    const float4* in1 = (const float4*)d_in[1];  // cd0_box1 [16,32768,8,8]
    const float4* in2 = (const float4*)d_in[2];  // cd1_box0 [16,32768,4,4]
    const float4* in3 = (const float4*)d_in[3];  // cd1_box1 [16,32768,8,8]
    int* ws = (int*)d_ws;

    hipMemsetAsync(ws, 0, 2560 * sizeof(int), stream);
    hist_kernel<<<2 * (NB0 + NB1), 256, 0, stream>>>(in0, in1, in2, in3, ws);
    norm_kernel<<<64, 64, 0, stream>>>(ws, (float*)d_out);
}

// Round 4
// 317.118 us; speedup vs baseline: 1.0270x; 1.0007x over previous
//
#include <hip/hip_runtime.h>

// ProbabilityMatrix: 4x row-histogram of per-patch popcounts, normalized.
// ws layout (ints) == out layout (floats), flat concat:
//   box0 [16][16] @ 0, box1 [16][64] @ 256, box2 [16][16] @ 1280, box3 [16][64] @ 1536

#define P_PATCH 32768
#define B_ROWS  16
#define NPATCH  (B_ROWS * P_PATCH)   // 524288 patches per box

// DPP-based partial add: s += dpp_perm(s). Pure VALU — no LDS, no ds_swizzle.
template <int CTRL>
__device__ __forceinline__ float dpp_add(float s) {
    int t = __builtin_amdgcn_update_dpp(0, __float_as_int(s), CTRL, 0xF, 0xF, true);
    return s + __int_as_float(t);
}
// quad_perm[1,0,3,2]=0xB1 (xor1), quad_perm[2,3,0,1]=0x4E (xor2),
// row_ror:4=0x124, row_ror:8=0x128 -> 16-lane all-reduce.

template <int FV, int LOG2FV>  // FV = float4 per patch (4 or 16)
__device__ __forceinline__ void hist_box(const float4* __restrict__ in,
                                         int* __restrict__ gcounts,
                                         int block_rank, int num_blocks,
                                         int* lds) {
    constexpr int S2  = FV * 4;
    constexpr int U   = 8;                     // float4 per thread per tile
    constexpr int HSZ = B_ROWS * S2;           // one histogram copy
    const int N4      = NPATCH * FV;           // 2^21 or 2^23 float4
    const int ntiles  = N4 / (256 * U);        // exact

    for (int i = threadIdx.x; i < 4 * HSZ; i += 256) lds[i] = 0;
    __syncthreads();

    const int  tid    = (int)threadIdx.x;
    const bool leader = (tid & (FV - 1)) == 0;
    int* hist = lds + ((tid >> 4) & 3) * HSZ;  // per-16-lane-group copy: no
                                               // same-address lanes in one ds_atomic (FV=16),
                                               // <=4 writers/copy (FV=4)

    int t = block_rank;
    float4 v[U];
    if (t < ntiles) {
        const float4* p = in + t * (256 * U) + tid;
#pragma unroll
        for (int k = 0; k < U; ++k) v[k] = p[k * 256];   // coalesced 1KB/wave-instr
    }

    while (t < ntiles) {
        const int tn = t + num_blocks;

        // Phase A: pure VALU — patch sums for current tile
        float s[U];
#pragma unroll
        for (int k = 0; k < U; ++k) {
            float x = (v[k].x + v[k].y) + (v[k].z + v[k].w);
            x = dpp_add<0xB1>(x);
            x = dpp_add<0x4E>(x);                 // quad sums
            if (FV == 16) {
                x = dpp_add<0x124>(x);
                x = dpp_add<0x128>(x);            // 16-lane sum, all lanes
            }
            s[k] = x;
        }
        const int base = t * (256 * U) + tid;

        // Phase B: issue ALL next-tile loads BEFORE any atomic (MLP=8/wave)
        if (tn < ntiles) {
            const float4* p = in + tn * (256 * U) + tid;
#pragma unroll
            for (int k = 0; k < U; ++k) v[k] = p[k * 256];
        }

        // Phase C: histogram atomics overlap the in-flight loads
        if (leader) {
#pragma unroll
            for (int k = 0; k < U; ++k) {
                const int q     = base + k * 256;
                const int patch = q >> LOG2FV;
                const int row   = patch >> 15;        // / P_PATCH
                const int bin   = (int)(s[k] + 0.5f); // exact: sum of 0/1 floats
                if (bin < S2)                         // drop popcount == S2 (TF semantics)
                    atomicAdd(&hist[row * S2 + bin], 1);
            }
        }
        t = tn;
    }
    __syncthreads();

    for (int i = threadIdx.x; i < HSZ; i += 256) {
        int c = lds[i] + lds[HSZ + i] + lds[2 * HSZ + i] + lds[3 * HSZ + i];
        if (c) atomicAdd(&gcounts[i], c);
    }
}

#define NB0 128
#define NB1 512
// grid = 2*(NB0+NB1) = 1280 blocks = 5 blocks/CU (fully co-resident), 8 tiles/block

__global__ __launch_bounds__(256) void hist_kernel(const float4* __restrict__ in0,
                                                   const float4* __restrict__ in1,
                                                   const float4* __restrict__ in2,
                                                   const float4* __restrict__ in3,
                                                   int* __restrict__ ws) {
    __shared__ int lds[4 * B_ROWS * 64];  // 16 KiB: 4 sub-histogram copies
    const int bid = blockIdx.x;
    if (bid < NB0)              hist_box<4, 2>(in0, ws + 0,    bid,               NB0, lds);
    else if (bid < NB0 + NB1)   hist_box<16,4>(in1, ws + 256,  bid - NB0,         NB1, lds);
    else if (bid < 2*NB0 + NB1) hist_box<4, 2>(in2, ws + 1280, bid - NB0 - NB1,   NB0, lds);
    else                        hist_box<16,4>(in3, ws + 1536, bid - 2*NB0 - NB1, NB1, lds);
}

// one 64-lane wave per (box,row): out[v] = counts[v] / rowsum
__global__ __launch_bounds__(64) void norm_kernel(const int* __restrict__ ws,
                                                  float* __restrict__ out) {
    const int row  = blockIdx.x;      // 0..63
    const int lane = threadIdx.x;     // 0..63
    const int box  = row >> 4;
    const int r    = row & 15;
    const int bins = (box & 1) ? 64 : 16;
    int off = (box == 0) ? 0 : (box == 1) ? 256 : (box == 2) ? 1280 : 1536;
    off += r * bins;

    int c = (lane < bins) ? ws[off + lane] : 0;
    int total = c;
#pragma unroll
    for (int d = 32; d > 0; d >>= 1) total += __shfl_down(total, d);
    total = __shfl(total, 0);

    if (lane < bins) out[off + lane] = (float)c / (float)total;
}

extern "C" void kernel_launch(void* const* d_in, const int* in_sizes, int n_in,
                              void* d_out, int out_size, void* d_ws, size_t ws_size,
                              hipStream_t stream) {
    const float4* in0 = (const float4*)d_in[0];  // cd0_box0 [16,32768,4,4]
    const float4* in1 = (const float4*)d_in[1];  // cd0_box1 [16,32768,8,8]
    const float4* in2 = (const float4*)d_in[2];  // cd1_box0 [16,32768,4,4]
    const float4* in3 = (const float4*)d_in[3];  // cd1_box1 [16,32768,8,8]
    int* ws = (int*)d_ws;

    hipMemsetAsync(ws, 0, 2560 * sizeof(int), stream);
    hist_kernel<<<2 * (NB0 + NB1), 256, 0, stream>>>(in0, in1, in2, in3, ws);
    norm_kernel<<<64, 64, 0, stream>>>(ws, (float*)d_out);
}